// Round 3
// baseline (7440.816 us; speedup 1.0000x reference)
//
#include <hip/hip_runtime.h>
#include <math.h>

// ---------------- tiled fp32 GEMM: C = (A @ B[^T]) * scale (+ bias) --------
// A: [M,K] row-major lda. B: NN -> [K,N] ldb; BT -> [N,K] ldb (dot of rows).
// Tiles: 64x64x16, 256 threads, 4x4 microtile. Exact tiling (no bounds checks):
// all M,N,K here are multiples of 64/64/16.
template<bool BT, bool HAS_BIAS>
__global__ __launch_bounds__(256)
void gemm_k(const float* __restrict__ A, const float* __restrict__ B,
            const float* __restrict__ bias, float* __restrict__ C,
            int K, int lda, int ldb, int ldc,
            long long sA, long long sB, long long sC, float scale)
{
    A += (long long)blockIdx.z * sA;
    B += (long long)blockIdx.z * sB;
    C += (long long)blockIdx.z * sC;
    const int bm = blockIdx.y * 64;
    const int bn = blockIdx.x * 64;
    const int tid = threadIdx.x;

    __shared__ float As[16][68];
    __shared__ float Bs[16][68];

    const int tm = tid & 15, tn = tid >> 4;
    const int m0 = tm * 4, n0 = tn * 4;

    const int la_m = tid >> 2;
    const int la_k = (tid & 3) * 4;
    const int lb_k = tid >> 4;
    const int lb_n = (tid & 15) * 4;

    float acc[4][4] = {};

    const int nkt = K >> 4;
    for (int kt = 0; kt < nkt; ++kt) {
        const int k0 = kt << 4;
        float4 av = *(const float4*)&A[(long long)(bm + la_m) * lda + k0 + la_k];
        float4 bv;
        if (BT) bv = *(const float4*)&B[(long long)(bn + la_m) * ldb + k0 + la_k];
        else    bv = *(const float4*)&B[(long long)(k0 + lb_k) * ldb + bn + lb_n];
        __syncthreads();
        As[la_k + 0][la_m] = av.x; As[la_k + 1][la_m] = av.y;
        As[la_k + 2][la_m] = av.z; As[la_k + 3][la_m] = av.w;
        if (BT) {
            Bs[la_k + 0][la_m] = bv.x; Bs[la_k + 1][la_m] = bv.y;
            Bs[la_k + 2][la_m] = bv.z; Bs[la_k + 3][la_m] = bv.w;
        } else {
            *(float4*)&Bs[lb_k][lb_n] = bv;
        }
        __syncthreads();
#pragma unroll
        for (int k = 0; k < 16; ++k) {
            float4 a = *(const float4*)&As[k][m0];
            float4 b = *(const float4*)&Bs[k][n0];
            acc[0][0] = fmaf(a.x, b.x, acc[0][0]); acc[0][1] = fmaf(a.x, b.y, acc[0][1]);
            acc[0][2] = fmaf(a.x, b.z, acc[0][2]); acc[0][3] = fmaf(a.x, b.w, acc[0][3]);
            acc[1][0] = fmaf(a.y, b.x, acc[1][0]); acc[1][1] = fmaf(a.y, b.y, acc[1][1]);
            acc[1][2] = fmaf(a.y, b.z, acc[1][2]); acc[1][3] = fmaf(a.y, b.w, acc[1][3]);
            acc[2][0] = fmaf(a.z, b.x, acc[2][0]); acc[2][1] = fmaf(a.z, b.y, acc[2][1]);
            acc[2][2] = fmaf(a.z, b.z, acc[2][2]); acc[2][3] = fmaf(a.z, b.w, acc[2][3]);
            acc[3][0] = fmaf(a.w, b.x, acc[3][0]); acc[3][1] = fmaf(a.w, b.y, acc[3][1]);
            acc[3][2] = fmaf(a.w, b.z, acc[3][2]); acc[3][3] = fmaf(a.w, b.w, acc[3][3]);
        }
    }

    float4 bb = make_float4(0.f, 0.f, 0.f, 0.f);
    if (HAS_BIAS) bb = *(const float4*)&bias[bn + n0];
#pragma unroll
    for (int i = 0; i < 4; ++i) {
        float4 o;
        o.x = fmaf(acc[i][0], scale, bb.x);
        o.y = fmaf(acc[i][1], scale, bb.y);
        o.z = fmaf(acc[i][2], scale, bb.z);
        o.w = fmaf(acc[i][3], scale, bb.w);
        *(float4*)&C[(long long)(bm + m0 + i) * ldc + bn + n0] = o;
    }
}

// ---------------- gw = softmax(V @ w_gp) over 49 groups, one wave per row ---
// 4 independent accumulators break the 768-deep dependent FMA chain.
__global__ __launch_bounds__(64)
void gw_k(const float* __restrict__ qkv, const float* __restrict__ wgp,
          float* __restrict__ gw)
{
    const long long row = blockIdx.x;
    const int lane = threadIdx.x;
    const float* v = qkv + row * 2304 + 1536;
    float a0 = 0.f, a1 = 0.f, a2 = 0.f, a3 = 0.f;
    if (lane < 49) {
        for (int d = 0; d < 768; d += 4) {
            a0 = fmaf(v[d + 0], wgp[(d + 0) * 49 + lane], a0);
            a1 = fmaf(v[d + 1], wgp[(d + 1) * 49 + lane], a1);
            a2 = fmaf(v[d + 2], wgp[(d + 2) * 49 + lane], a2);
            a3 = fmaf(v[d + 3], wgp[(d + 3) * 49 + lane], a3);
        }
    }
    float logit = (lane < 49) ? ((a0 + a1) + (a2 + a3)) : -INFINITY;
    float m = logit;
    for (int off = 32; off; off >>= 1)
        m = fmaxf(m, __shfl_xor(m, off, 64));
    float e = (lane < 49) ? expf(logit - m) : 0.f;
    float s = e;
    for (int off = 32; off; off >>= 1)
        s += __shfl_xor(s, off, 64);
    if (lane < 49) gw[row * 49 + lane] = e / s;
}

// ---------------- fused softmax * G modulation, in place on S --------------
// attn_qk = w*c/(c*T+eps), w = exp(s-m)*G_qk, G_qk = gw_q . gw_k,
// c = n/(Z*(SG+eps)); Z,SG,T row sums of exp, G, w. Same math as R2 (passed),
// restructured: 8 q-rows/block, gw_k staged via LDS in 128-row tiles, gw_q in
// registers, S row held in 32 VGPRs, 32-lane shuffle reductions.
__global__ __launch_bounds__(256)
void mod_k2(float* __restrict__ S, const float* __restrict__ gw)
{
    const int qb   = blockIdx.x;          // 0..127 -> 8 q rows each
    const int b    = blockIdx.y;          // chunk-local batch
    const int tid  = threadIdx.x;
    const int ql   = tid >> 5;            // 0..7  (32 threads per q row)
    const int l32  = tid & 31;

    float* Sq = S + ((long long)b * 1024 + (qb * 8 + ql)) * 1024;
    const float* gwb = gw + (long long)b * 1024 * 49;

    __shared__ float gwT[128][50];        // k-tile of gw rows, +pad slot [49]=0
    __shared__ float gwqL[8][50];         // this block's 8 q rows of gw

    for (int idx = tid; idx < 8 * 49; idx += 256) {
        int r = idx / 49, c2 = idx - r * 49;
        gwqL[r][c2] = gwb[(qb * 8 + r) * 49 + c2];
    }
    if (tid < 8) gwqL[tid][49] = 0.f;
    __syncthreads();

    float2 gq[25];
#pragma unroll
    for (int j = 0; j < 25; ++j)
        gq[j] = ((const float2*)&gwqL[ql][0])[j];

    // phase 1: read S row chunk, row max over 32 lanes
    float s[32];
    float m = -INFINITY;
#pragma unroll
    for (int i = 0; i < 32; ++i) {
        s[i] = Sq[l32 + 32 * i];
        m = fmaxf(m, s[i]);
    }
#pragma unroll
    for (int off = 16; off; off >>= 1)
        m = fmaxf(m, __shfl_xor(m, off, 64));

    // phase 2: exp in place, partial Z
    float Z = 0.f;
#pragma unroll
    for (int i = 0; i < 32; ++i) { s[i] = expf(s[i] - m); Z += s[i]; }

    // phase 3: G dots from LDS tiles, w = e*g in place
    float SG = 0.f, T = 0.f;
#pragma unroll
    for (int kt = 0; kt < 8; ++kt) {
        __syncthreads();                  // protect gwT from previous readers
        for (int idx = tid; idx < 128 * 49; idx += 256) {
            int r = idx / 49, c2 = idx - r * 49;
            gwT[r][c2] = gwb[(kt * 128 + r) * 49 + c2];
        }
        if (tid < 128) gwT[tid][49] = 0.f;
        __syncthreads();
#pragma unroll
        for (int ii = 0; ii < 4; ++ii) {
            const int i  = kt * 4 + ii;
            const int kl = l32 + 32 * ii;
            const float2* rowp = (const float2*)&gwT[kl][0];
            float gx = 0.f, gy = 0.f;
#pragma unroll
            for (int j = 0; j < 25; ++j) {
                float2 bv = rowp[j];
                gx = fmaf(gq[j].x, bv.x, gx);
                gy = fmaf(gq[j].y, bv.y, gy);
            }
            float g = gx + gy;
            float w = s[i] * g;
            SG += g; T += w; s[i] = w;
        }
    }

    // phase 4: 32-lane reductions, normalize, write back
#pragma unroll
    for (int off = 16; off; off >>= 1) {
        Z  += __shfl_xor(Z,  off, 64);
        SG += __shfl_xor(SG, off, 64);
        T  += __shfl_xor(T,  off, 64);
    }
    const float c = 1024.f / (Z * (SG + 1e-8f));
    const float f = c / (c * T + 1e-8f);
#pragma unroll
    for (int i = 0; i < 32; ++i)
        Sq[l32 + 32 * i] = s[i] * f;
}

extern "C" void kernel_launch(void* const* d_in, const int* in_sizes, int n_in,
                              void* d_out, int out_size, void* d_ws, size_t ws_size,
                              hipStream_t stream)
{
    const float* x      = (const float*)d_in[0];   // [32,1024,768]
    const float* w_qkv  = (const float*)d_in[1];   // [768,2304]
    const float* b_qkv  = (const float*)d_in[2];   // [2304]
    const float* w_proj = (const float*)d_in[3];   // [768,768]
    const float* b_proj = (const float*)d_in[4];   // [768]
    const float* w_gp   = (const float*)d_in[5];   // [768,49]
    float* out = (float*)d_out;
    float* ws  = (float*)d_ws;

    // Batch-chunked pipeline: CB=4 batches per chunk, scratch reused.
    // qkvC [4096,2304] | SC [4,1024,1024] | gwC [4096,49]  = 55.3 MB total
    const int  CB = 4;
    const int  MC = CB * 1024;
    float* qkvC = ws;
    float* SC   = ws + 9437184LL;
    float* gwC  = ws + 13631488LL;

    const long long sQKV = 1024LL * 2304;
    const long long sS   = 1024LL * 1024;
    const float scale = 1.0f / sqrtf(768.0f);

    for (int c = 0; c < 32 / CB; ++c) {
        const float* xc   = x   + (long long)c * MC * 768;
        float*       outc = out + (long long)c * MC * 768;

        // 1) qkvC = xc @ w_qkv + b_qkv   [4096 x 2304], K=768
        gemm_k<false, true><<<dim3(36, MC / 64, 1), 256, 0, stream>>>(
            xc, w_qkv, b_qkv, qkvC, 768, 768, 2304, 2304, 0, 0, 0, 1.0f);

        // 2) gwC = softmax(V @ w_gp)
        gw_k<<<dim3(MC), 64, 0, stream>>>(qkvC, w_gp, gwC);

        // 3) SC = Q @ K^T * scale   per batch [1024 x 1024], K=768
        gemm_k<true, false><<<dim3(16, 16, CB), 256, 0, stream>>>(
            qkvC, qkvC + 768, nullptr, SC, 768, 2304, 2304, 1024, sQKV, sQKV, sS, scale);

        // 4) attn = normalize(softmax(SC) * G) in place
        mod_k2<<<dim3(128, CB), 256, 0, stream>>>(SC, gwC);

        // 5) O = attn @ V  -> aliased onto Q columns of qkvC (Q dead now)
        gemm_k<false, false><<<dim3(12, 16, CB), 256, 0, stream>>>(
            SC, qkvC + 1536, nullptr, qkvC, 1024, 1024, 2304, 2304, sS, sQKV, sQKV, 1.0f);

        // 6) outc = O @ w_proj + b_proj   [4096 x 768], K=768
        gemm_k<false, true><<<dim3(12, MC / 64, 1), 256, 0, stream>>>(
            qkvC, w_proj, b_proj, outc, 768, 2304, 768, 768, 0, 0, 0, 1.0f);
    }
}

// Round 4
// 2530.055 us; speedup vs baseline: 2.9410x; 2.9410x over previous
//
#include <hip/hip_runtime.h>
#include <math.h>

typedef short  bf16x8 __attribute__((ext_vector_type(8)));
typedef float  f32x4  __attribute__((ext_vector_type(4)));

__device__ __forceinline__ unsigned short bf16_rn(float x) {
    unsigned u = __float_as_uint(x);
    u += 0x7fffu + ((u >> 16) & 1u);
    return (unsigned short)(u >> 16);
}
__device__ __forceinline__ float bf16f(unsigned short h) {
    return __uint_as_float(((unsigned)h) << 16);
}

// ==================== MFMA split-bf16 GEMM =================================
// C = scale*(A@B) [+ bias], computed as Ah*Bh + Ah*Bl + Al*Bh on bf16 MFMA
// (dropped Al*Bl term ~2^-16 relative -- fp32-grade accuracy).
// A operand: [M][K] rows (hi/lo bf16, or fp32 split on the fly if A_F32).
// B operand: [N][K] rows (hi/lo bf16) -- i.e. B^T storage, dot-of-rows.
// Tile 128x128, BK=32, 256 threads = 4 waves in 2x2, each wave 4x4 of
// 16x16x32 MFMA. LDS layout per array: [blk 8][kg 4][row 16][8 bf16] (8KB).
// A and B share lda == K for all call sites (packed operands).
// OUTM: 0 = fp32 C (o1)    1 = qkv epilogue (o1..o5 = Qh,Ql,Kh,Kl,Vfp32)
//       2 = hi/lo bf16 (o1,o2)
template<int OUTM, bool HAS_BIAS, bool A_F32>
__global__ __launch_bounds__(256, 2)
void mgemm(const void* A_, const unsigned short* __restrict__ Al_,
           const unsigned short* __restrict__ Bh_, const unsigned short* __restrict__ Bl_,
           const float* __restrict__ bias,
           void* o1, void* o2, void* o3, void* o4, void* o5,
           int K, int lda, int ldc,
           long long sA, long long sB, long long sC, float scale)
{
    const int tid = threadIdx.x;
    const int bm = blockIdx.y * 128;
    const int bn = blockIdx.x * 128;
    const long long z = blockIdx.z;

    const float*          Af  = (const float*)A_ + z * sA;          // A_F32
    const unsigned short* Ahu = (const unsigned short*)A_ + z * sA; // bf16
    const unsigned short* Alu = Al_ + z * sA;
    const unsigned short* Bhu = Bh_ + z * sB;
    const unsigned short* Blu = Bl_ + z * sB;

    __shared__ unsigned short LA_h[4096], LA_l[4096], LB_h[4096], LB_l[4096];

    const int wv = tid >> 6, wr = wv >> 1, wc = wv & 1, lane = tid & 63;
    const int fro = (lane >> 4) * 128 + (lane & 15) * 8;  // frag offset in blk

    f32x4 acc[4][4];
#pragma unroll
    for (int i = 0; i < 4; ++i)
#pragma unroll
        for (int j = 0; j < 4; ++j) acc[i][j] = (f32x4){0.f, 0.f, 0.f, 0.f};

    const int nkt = K >> 5;
    for (int kt = 0; kt < nkt; ++kt) {
        const int k0 = kt << 5;
        __syncthreads();                          // readers of prev tile done
        // ---- stage A (2 x 16B chunks per thread per array) ----
        if (A_F32) {
#pragma unroll
            for (int rep = 0; rep < 2; ++rep) {
                int c = tid + rep * 256;
                int kg = c & 3, row = (c >> 2) & 15, blk = c >> 6;
                const float* gp = Af + (size_t)(bm + 16 * blk + row) * lda + k0 + kg * 8;
                float4 f0 = *(const float4*)gp;
                float4 f1 = *(const float4*)(gp + 4);
                float ff[8] = {f0.x, f0.y, f0.z, f0.w, f1.x, f1.y, f1.z, f1.w};
                bf16x8 hv, lv;
#pragma unroll
                for (int j = 0; j < 8; ++j) {
                    unsigned short h = bf16_rn(ff[j]);
                    hv[j] = (short)h;
                    lv[j] = (short)bf16_rn(ff[j] - bf16f(h));
                }
                int off = blk * 512 + kg * 128 + row * 8;
                *(bf16x8*)&LA_h[off] = hv;
                *(bf16x8*)&LA_l[off] = lv;
            }
        } else {
#pragma unroll
            for (int rep = 0; rep < 2; ++rep) {
                int c = tid + rep * 256;
                int kg = c & 3, row = (c >> 2) & 15, blk = c >> 6;
                size_t ga = (size_t)(bm + 16 * blk + row) * lda + k0 + kg * 8;
                int off = blk * 512 + kg * 128 + row * 8;
                *(uint4*)&LA_h[off] = *(const uint4*)&Ahu[ga];
                *(uint4*)&LA_l[off] = *(const uint4*)&Alu[ga];
            }
        }
        // ---- stage B ----
#pragma unroll
        for (int rep = 0; rep < 2; ++rep) {
            int c = tid + rep * 256;
            int kg = c & 3, row = (c >> 2) & 15, blk = c >> 6;
            size_t ga = (size_t)(bn + 16 * blk + row) * lda + k0 + kg * 8;
            int off = blk * 512 + kg * 128 + row * 8;
            *(uint4*)&LB_h[off] = *(const uint4*)&Bhu[ga];
            *(uint4*)&LB_l[off] = *(const uint4*)&Blu[ga];
        }
        __syncthreads();                          // staging visible
        // ---- compute: 48 MFMA per wave per BK=32 ----
        bf16x8 bhf[4], blf[4];
#pragma unroll
        for (int ni = 0; ni < 4; ++ni) {
            int off = (wc * 4 + ni) * 512 + fro;
            bhf[ni] = *(const bf16x8*)&LB_h[off];
            blf[ni] = *(const bf16x8*)&LB_l[off];
        }
#pragma unroll
        for (int mi = 0; mi < 4; ++mi) {
            int off = (wr * 4 + mi) * 512 + fro;
            bf16x8 ah = *(const bf16x8*)&LA_h[off];
            bf16x8 al = *(const bf16x8*)&LA_l[off];
#pragma unroll
            for (int ni = 0; ni < 4; ++ni) {
                f32x4 a = acc[mi][ni];
                a = __builtin_amdgcn_mfma_f32_16x16x32_bf16(ah, bhf[ni], a, 0, 0, 0);
                a = __builtin_amdgcn_mfma_f32_16x16x32_bf16(ah, blf[ni], a, 0, 0, 0);
                a = __builtin_amdgcn_mfma_f32_16x16x32_bf16(al, bhf[ni], a, 0, 0, 0);
                acc[mi][ni] = a;
            }
        }
    }

    // ---- epilogue: C/D layout col=lane&15, row=(lane>>4)*4+r ----
#pragma unroll
    for (int mi = 0; mi < 4; ++mi) {
#pragma unroll
        for (int ni = 0; ni < 4; ++ni) {
            const int grow0 = bm + wr * 64 + mi * 16 + ((lane >> 4) << 2);
            const int gcol  = bn + wc * 64 + ni * 16 + (lane & 15);
            float bb = HAS_BIAS ? bias[gcol] : 0.f;
#pragma unroll
            for (int r = 0; r < 4; ++r) {
                float v = acc[mi][ni][r] * scale + bb;
                const size_t grow = (size_t)(grow0 + r);
                if (OUTM == 0) {
                    ((float*)o1 + z * sC)[grow * ldc + gcol] = v;
                } else if (OUTM == 1) {
                    if (gcol < 768) {
                        unsigned short h = bf16_rn(v);
                        ((unsigned short*)o1)[grow * 768 + gcol] = h;
                        ((unsigned short*)o2)[grow * 768 + gcol] = bf16_rn(v - bf16f(h));
                    } else if (gcol < 1536) {
                        int cc = gcol - 768;
                        unsigned short h = bf16_rn(v);
                        ((unsigned short*)o3)[grow * 768 + cc] = h;
                        ((unsigned short*)o4)[grow * 768 + cc] = bf16_rn(v - bf16f(h));
                    } else {
                        ((float*)o5)[grow * 768 + (gcol - 1536)] = v;
                    }
                } else {
                    unsigned short h = bf16_rn(v);
                    ((unsigned short*)o1 + z * sC)[grow * ldc + gcol] = h;
                    ((unsigned short*)o2 + z * sC)[grow * ldc + gcol] = bf16_rn(v - bf16f(h));
                }
            }
        }
    }
}

// ==================== transpose + split to hi/lo bf16 ======================
// src fp32 [R][C] (ld ls) -> dh/dl bf16 [C][R] (ld ld_)
__global__ __launch_bounds__(256)
void tsplit_k(const float* __restrict__ src, unsigned short* __restrict__ dh,
              unsigned short* __restrict__ dl, int ls, long long ss,
              int ld_, long long sd)
{
    src += (long long)blockIdx.z * ss;
    dh  += (long long)blockIdx.z * sd;
    dl  += (long long)blockIdx.z * sd;
    __shared__ float t[32][33];
    const int tx = threadIdx.x & 31, ty = threadIdx.x >> 5;
    const int r0 = blockIdx.y * 32, c0 = blockIdx.x * 32;
#pragma unroll
    for (int i = 0; i < 4; ++i)
        t[ty + 8 * i][tx] = src[(size_t)(r0 + ty + 8 * i) * ls + c0 + tx];
    __syncthreads();
#pragma unroll
    for (int i = 0; i < 4; ++i) {
        float v = t[tx][ty + 8 * i];
        unsigned short h = bf16_rn(v);
        size_t o = (size_t)(c0 + ty + 8 * i) * ld_ + r0 + tx;
        dh[o] = h;
        dl[o] = bf16_rn(v - bf16f(h));
    }
}

// ==================== gw = softmax(V @ w_gp), one wave per row =============
__global__ __launch_bounds__(64)
void gw_k(const float* __restrict__ Vf, const float* __restrict__ wgp,
          float* __restrict__ gw)
{
    const long long row = blockIdx.x;
    const int lane = threadIdx.x;
    const float* v = Vf + row * 768;
    float a0 = 0.f, a1 = 0.f, a2 = 0.f, a3 = 0.f;
    if (lane < 49) {
        for (int d = 0; d < 768; d += 4) {
            float4 vv = *(const float4*)&v[d];
            a0 = fmaf(vv.x, wgp[(d + 0) * 49 + lane], a0);
            a1 = fmaf(vv.y, wgp[(d + 1) * 49 + lane], a1);
            a2 = fmaf(vv.z, wgp[(d + 2) * 49 + lane], a2);
            a3 = fmaf(vv.w, wgp[(d + 3) * 49 + lane], a3);
        }
    }
    float logit = (lane < 49) ? ((a0 + a1) + (a2 + a3)) : -INFINITY;
    float m = logit;
    for (int off = 32; off; off >>= 1) m = fmaxf(m, __shfl_xor(m, off));
    float e = (lane < 49) ? expf(logit - m) : 0.f;
    float s = e;
    for (int off = 32; off; off >>= 1) s += __shfl_xor(s, off);
    if (lane < 49) gw[row * 49 + lane] = e / s;
}

// ==================== fused softmax*G modulation, streaming ================
// attn = w*c/(c*T+eps), w = exp(s-m)*(gw_q.gw_k), c = n/(Z*(SG+eps)).
// 8 q rows/block, 32 threads/row; 3 streaming passes over S (L1/L2-hot)
// keep per-thread state ~20 VGPRs (R3's spill fix). Emits bf16 hi/lo attn.
__global__ __launch_bounds__(256)
void mod_k3(float* __restrict__ S, const float* __restrict__ gw,
            unsigned short* __restrict__ Sh, unsigned short* __restrict__ Sl)
{
    const int qb  = blockIdx.x;           // 0..127
    const int b   = blockIdx.y;           // chunk-local batch
    const int tid = threadIdx.x;
    const int ql  = tid >> 5;             // 0..7
    const int l32 = tid & 31;

    const long long rowg = (long long)b * 1024 + (qb * 8 + ql);
    float* Srow = S + rowg * 1024;
    const float* gwb = gw + (long long)b * 1024 * 49;

    __shared__ float gwqL[8][50];
    __shared__ float gwT[128][50];

    for (int idx = tid; idx < 8 * 49; idx += 256) {
        int r = idx / 49, c2 = idx - r * 49;
        gwqL[r][c2] = gwb[(qb * 8 + r) * 49 + c2];
    }
    if (tid < 8) gwqL[tid][49] = 0.f;
    __syncthreads();

    // pass A: row max
    float m = -INFINITY;
#pragma unroll
    for (int i = 0; i < 32; ++i) m = fmaxf(m, Srow[l32 + 32 * i]);
#pragma unroll
    for (int off = 16; off; off >>= 1) m = fmaxf(m, __shfl_xor(m, off));

    // pass B: w = e*g written back to S; accumulate Z, SG, T
    float Z = 0.f, SG = 0.f, T = 0.f;
    const float2* gq = (const float2*)&gwqL[ql][0];
    for (int kt = 0; kt < 8; ++kt) {
        __syncthreads();
        for (int idx = tid; idx < 128 * 49; idx += 256) {
            int r = idx / 49, c2 = idx - r * 49;
            gwT[r][c2] = gwb[(kt * 128 + r) * 49 + c2];
        }
        if (tid < 128) gwT[tid][49] = 0.f;
        __syncthreads();
#pragma unroll
        for (int ii = 0; ii < 4; ++ii) {
            const int kl = l32 + 32 * ii;
            const int k  = kt * 128 + kl;
            float e = expf(Srow[k] - m);
            const float2* rowp = (const float2*)&gwT[kl][0];
            float gx = 0.f, gy = 0.f;
#pragma unroll
            for (int j = 0; j < 25; ++j) {
                float2 bv = rowp[j];
                float2 qv = gq[j];
                gx = fmaf(qv.x, bv.x, gx);
                gy = fmaf(qv.y, bv.y, gy);
            }
            float g = gx + gy;
            float w = e * g;
            Z += e; SG += g; T += w;
            Srow[k] = w;
        }
    }
#pragma unroll
    for (int off = 16; off; off >>= 1) {
        Z  += __shfl_xor(Z,  off);
        SG += __shfl_xor(SG, off);
        T  += __shfl_xor(T,  off);
    }
    const float c = 1024.f / (Z * (SG + 1e-8f));
    const float f = c / (c * T + 1e-8f);

    // pass C: final attn as bf16 hi/lo
    unsigned short* ShR = Sh + rowg * 1024;
    unsigned short* SlR = Sl + rowg * 1024;
#pragma unroll
    for (int i = 0; i < 32; ++i) {
        const int k = l32 + 32 * i;
        float v = Srow[k] * f;
        unsigned short h = bf16_rn(v);
        ShR[k] = h;
        SlR[k] = bf16_rn(v - bf16f(h));
    }
}

// ==================== launcher =============================================
extern "C" void kernel_launch(void* const* d_in, const int* in_sizes, int n_in,
                              void* d_out, int out_size, void* d_ws, size_t ws_size,
                              hipStream_t stream)
{
    const float* x      = (const float*)d_in[0];   // [32,1024,768]
    const float* w_qkv  = (const float*)d_in[1];   // [768,2304]
    const float* b_qkv  = (const float*)d_in[2];   // [2304]
    const float* w_proj = (const float*)d_in[3];   // [768,768]
    const float* b_proj = (const float*)d_in[4];   // [768]
    const float* w_gp   = (const float*)d_in[5];   // [768,49]
    float* out = (float*)d_out;

    // ---- CB-adaptive workspace (ws budget unknown; R2 proved >=55.3MB) ----
    auto need = [](int CB) -> size_t {
        size_t u = 0;
        u += 2ull * 2304 * 768;            // WqT h+l
        u += 2ull * 768 * 768;             // WpT h+l
        u += 4ull * CB * 1024 * 768;       // Qh,Ql,Kh,Kl (O aliases Q)
        u += 2ull * CB * 1024 * 768;       // VTh,VTl
        u += 2ull * CB * 1024 * 1024;      // Sh,Sl
        size_t bytes = u * 2;
        bytes += 4ull * ((size_t)CB * 1024 * 768      // Vf
                       + (size_t)CB * 1024 * 1024     // SC
                       + (size_t)CB * 1024 * 49);     // gw
        return bytes + 4096;
    };
    int CB = 4;
    if (need(4) > ws_size) CB = (need(2) <= ws_size) ? 2 : 1;
    const int MC = CB * 1024;

    char* cur = (char*)d_ws;
    auto alloc_u = [&](size_t n) {
        unsigned short* p = (unsigned short*)cur;
        cur += ((n * 2 + 15) & ~15ull);
        return p;
    };
    auto alloc_f = [&](size_t n) {
        float* p = (float*)cur;
        cur += ((n * 4 + 15) & ~15ull);
        return p;
    };
    unsigned short* WqTh = alloc_u(2304ull * 768);
    unsigned short* WqTl = alloc_u(2304ull * 768);
    unsigned short* WpTh = alloc_u(768ull * 768);
    unsigned short* WpTl = alloc_u(768ull * 768);
    unsigned short* Qh   = alloc_u((size_t)MC * 768);
    unsigned short* Ql   = alloc_u((size_t)MC * 768);
    unsigned short* Kh   = alloc_u((size_t)MC * 768);
    unsigned short* Kl   = alloc_u((size_t)MC * 768);
    unsigned short* VTh  = alloc_u((size_t)MC * 768);
    unsigned short* VTl  = alloc_u((size_t)MC * 768);
    unsigned short* Sh   = alloc_u((size_t)MC * 1024);
    unsigned short* Sl   = alloc_u((size_t)MC * 1024);
    float* Vf  = alloc_f((size_t)MC * 768);
    float* SC  = alloc_f((size_t)MC * 1024);
    float* gwC = alloc_f((size_t)MC * 49);
    unsigned short* Oh = Qh;   // O aliases Q (Q dead after GEMM S=QK^T)
    unsigned short* Ol = Ql;

    const float scale = 1.0f / sqrtf(768.0f);

    // ---- weight prep (once per launch) ----
    tsplit_k<<<dim3(72, 24, 1), 256, 0, stream>>>(w_qkv, WqTh, WqTl, 2304, 0, 768, 0);
    tsplit_k<<<dim3(24, 24, 1), 256, 0, stream>>>(w_proj, WpTh, WpTl, 768, 0, 768, 0);

    for (int c = 0; c < 32 / CB; ++c) {
        const float* xc   = x   + (size_t)c * MC * 768;
        float*       outc = out + (size_t)c * MC * 768;

        // 1) qkv GEMM: A = xc fp32 (split in-kernel), B = WqT.
        //    Epilogue writes Qh/Ql, Kh/Kl (bf16 hi/lo) and Vf (fp32).
        mgemm<1, true, true><<<dim3(18, MC / 128, 1), 256, 0, stream>>>(
            xc, nullptr, WqTh, WqTl, b_qkv,
            Qh, Ql, Kh, Kl, Vf, 768, 768, 0, 0, 0, 0, 1.0f);

        // 2) gw = softmax(V @ w_gp)
        gw_k<<<dim3(MC), 64, 0, stream>>>(Vf, w_gp, gwC);

        // 3) V^T hi/lo per batch (for attn@V's B operand)
        tsplit_k<<<dim3(24, 32, CB), 256, 0, stream>>>(
            Vf, VTh, VTl, 768, 1024ll * 768, 1024, 768ll * 1024);

        // 4) S = Q @ K^T * scale (per batch)
        mgemm<0, false, false><<<dim3(8, 8, CB), 256, 0, stream>>>(
            Qh, Ql, Kh, Kl, nullptr,
            SC, nullptr, nullptr, nullptr, nullptr,
            768, 768, 1024, 1024ll * 768, 1024ll * 768, 1024ll * 1024, scale);

        // 5) attn = normalize(softmax(S)*G) -> Sh/Sl (bf16 hi/lo)
        mod_k3<<<dim3(128, CB), 256, 0, stream>>>(SC, gwC, Sh, Sl);

        // 6) O = attn @ V (per batch) -> Oh/Ol
        mgemm<2, false, false><<<dim3(6, 8, CB), 256, 0, stream>>>(
            Sh, Sl, VTh, VTl, nullptr,
            Oh, Ol, nullptr, nullptr, nullptr,
            1024, 1024, 768, 1024ll * 1024, 768ll * 1024, 1024ll * 768, 1.0f);

        // 7) out = O @ w_proj + b_proj
        mgemm<0, true, false><<<dim3(6, MC / 128, 1), 256, 0, stream>>>(
            Oh, Ol, WpTh, WpTl, b_proj,
            outc, nullptr, nullptr, nullptr, nullptr,
            768, 768, 768, 0, 0, 0, 1.0f);
    }
}